// Round 4
// baseline (198.023 us; speedup 1.0000x reference)
//
#include <hip/hip_runtime.h>
#include <math.h>

// Problem constants (B=16, C=8, H=512, W=512)
#define HW        262144      // 512*512
#define HWQ       65536       // HW/4  (channel stride in float4 units)
#define CHW       2097152     // 8*HW  (batch stride in floats)
#define NBLOCKS   1024
#define NTHREADS  256
#define ITERS     4           // float4-groups per thread; 1024*256*4 == B*HW/4
#define TOTAL_PX  4194304.0f  // B*H*W

// ws layout (u32 indices):
//   ws[0]               : block-completion counter (starts at poison P)
//   ws[64 + c*32]       : class bin c (c=0..7), each on its own 128B line
//   ws[8192]            : untouched poison reference (P)
// The harness re-poisons ws with a uniform dword pattern before EVERY timed
// iteration, so counter/bins reset each iteration; all arithmetic is
// poison-relative with unsigned wraparound.
#define WS_CTR     0
#define WS_BIN0    64
#define WS_BINSTR  32
#define WS_PREF    8192

typedef float v4f __attribute__((ext_vector_type(4)));

// Single fused kernel. Cross-block communication is EXCLUSIVELY device-scope
// atomics, release-ordered by consuming the atomic returns (sc0 form) + an
// inline s_waitcnt vmcnt(0) -- NO __threadfence (round-2: per-wave L2
// writeback/inv was a 176us stall).
// Loads are PLAIN (cached) float4: the same 134 MB input is re-read every
// timed iteration and the 256 MiB Infinity Cache demonstrably retains ~half
// of it even across the poison fills (round-2 FETCH_SIZE = 64 MB of 128 MiB;
// replays with no fills: ~0). The previous nontemporal hint (evict-first)
// was fighting that reuse.
__global__ __launch_bounds__(NTHREADS, 4)
void argmax_hist_fused(const float* __restrict__ masks,
                       const float* __restrict__ prev,
                       float* __restrict__ out,
                       unsigned int* __restrict__ ws) {
    const int tid   = threadIdx.x;
    const int b     = blockIdx.x >> 6;          // 64 blocks per batch image
    const int gbase = (blockIdx.x & 63) << 10;  // group offset within image (float4 units)
    const float* bp = masks + (size_t)b * CHW;

    int cnt0 = 0, cnt1 = 0, cnt2 = 0, cnt3 = 0;
    int cnt4 = 0, cnt5 = 0, cnt6 = 0, cnt7 = 0;

    #pragma unroll
    for (int it = 0; it < ITERS; ++it) {
        const v4f* p = (const v4f*)(bp + (size_t)((gbase + it * NTHREADS + tid) << 2));

        // 8 independent 16B cached loads (input is re-read every iteration;
        // let L2/LLC retain it)
        v4f v0 = p[0 * HWQ];
        v4f v1 = p[1 * HWQ];
        v4f v2 = p[2 * HWQ];
        v4f v3 = p[3 * HWQ];
        v4f v4 = p[4 * HWQ];
        v4f v5 = p[5 * HWQ];
        v4f v6 = p[6 * HWQ];
        v4f v7 = p[7 * HWQ];

        float bv0 = v0.x, bv1 = v0.y, bv2 = v0.z, bv3 = v0.w;
        int   bi0 = 0,    bi1 = 0,    bi2 = 0,    bi3 = 0;

        // strict > : first occurrence of max wins (jnp.argmax semantics)
        #define STEP(vv, c)                                                         \
            bi0 = ((vv).x > bv0) ? (c) : bi0;  bv0 = ((vv).x > bv0) ? (vv).x : bv0; \
            bi1 = ((vv).y > bv1) ? (c) : bi1;  bv1 = ((vv).y > bv1) ? (vv).y : bv1; \
            bi2 = ((vv).z > bv2) ? (c) : bi2;  bv2 = ((vv).z > bv2) ? (vv).z : bv2; \
            bi3 = ((vv).w > bv3) ? (c) : bi3;  bv3 = ((vv).w > bv3) ? (vv).w : bv3;
        STEP(v1, 1) STEP(v2, 2) STEP(v3, 3) STEP(v4, 4)
        STEP(v5, 5) STEP(v6, 6) STEP(v7, 7)
        #undef STEP

        // ballot histogram: wave-uniform counts via v_cmp -> s_bcnt1
        #define COUNT(k, acc)                                                        \
            acc += __popcll(__ballot(bi0 == (k))) + __popcll(__ballot(bi1 == (k)))   \
                 + __popcll(__ballot(bi2 == (k))) + __popcll(__ballot(bi3 == (k)));
        COUNT(0, cnt0) COUNT(1, cnt1) COUNT(2, cnt2) COUNT(3, cnt3)
        COUNT(4, cnt4) COUNT(5, cnt5) COUNT(6, cnt6) COUNT(7, cnt7)
        #undef COUNT
    }

    const int lane = tid & 63;
    const int wid  = tid >> 6;
    __shared__ int lds[32];            // [4 waves][8 classes]
    __shared__ unsigned int lastflag;
    __shared__ float q[8];

    if (lane == 0) {
        lds[wid * 8 + 0] = cnt0;  lds[wid * 8 + 1] = cnt1;
        lds[wid * 8 + 2] = cnt2;  lds[wid * 8 + 3] = cnt3;
        lds[wid * 8 + 4] = cnt4;  lds[wid * 8 + 5] = cnt5;
        lds[wid * 8 + 6] = cnt6;  lds[wid * 8 + 7] = cnt7;
    }
    __syncthreads();

    // wave 0 only: bins -> device-scope atomics, then release-order the
    // counter add via vmcnt(0) (no cache-maintenance fence needed).
    if (tid < 64) {
        unsigned int old0 = 0u;
        if (tid < 8) {
            unsigned int s = (unsigned int)(lds[tid] + lds[8 + tid] + lds[16 + tid] + lds[24 + tid]);
            old0 = atomicAdd(&ws[WS_BIN0 + tid * WS_BINSTR], s);  // return consumed -> sc0
        }
        asm volatile("" : "+v"(old0));                 // keep return live (forces sc0 form)
        asm volatile("s_waitcnt vmcnt(0)" ::: "memory"); // bin RMWs completed at coherence point
        if (tid == 0) {
            unsigned int old = atomicAdd(&ws[WS_CTR], 1u);
            unsigned int P   = *(volatile unsigned int*)(ws + WS_PREF);
            lastflag = (old - P == (unsigned int)(NBLOCKS - 1)) ? 1u : 0u;
        }
    }
    __syncthreads();

    if (lastflag) {      // exactly one block (unique atomic return values)
        if (tid < 8) {
            unsigned int P = *(volatile unsigned int*)(ws + WS_PREF);
            unsigned int h = atomicAdd(&ws[WS_BIN0 + tid * WS_BINSTR], 0u) - P;  // coherent RMW read
            // exact: h <= 4194304 < 2^24
            float dist = prev[tid] * 0.99f + 0.01f * (float)h / TOTAL_PX;
            out[1 + tid] = dist;
            float d = (dist - 0.125f) / 0.875f;
            q[tid] = d * d;
        }
        __syncthreads();  // block-uniform branch: safe
        if (tid == 0) {
            float acc = 0.0f;
            #pragma unroll
            for (int k = 0; k < 8; ++k) acc += q[k];
            out[0] = sqrtf(acc);
        }
    }
}

extern "C" void kernel_launch(void* const* d_in, const int* in_sizes, int n_in,
                              void* d_out, int out_size, void* d_ws, size_t ws_size,
                              hipStream_t stream) {
    const float* masks = (const float*)d_in[0];   // [16,8,512,512] fp32
    const float* prev  = (const float*)d_in[1];   // [8] fp32
    float* out = (float*)d_out;                   // [9]: balance, dist[0..7]
    unsigned int* ws = (unsigned int*)d_ws;       // counter + bins + poison ref

    argmax_hist_fused<<<NBLOCKS, NTHREADS, 0, stream>>>(masks, prev, out, ws);
}

// Round 5
// 185.712 us; speedup vs baseline: 1.0663x; 1.0663x over previous
//
#include <hip/hip_runtime.h>
#include <math.h>

// Problem constants (B=16, C=8, H=512, W=512)
#define HW        262144      // 512*512
#define HWQ       65536       // HW/4  (channel stride in float4 units)
#define CHW       2097152     // 8*HW  (batch stride in floats)
#define NBLOCKS   1024
#define NTHREADS  256
#define ITERS     4           // float4-groups per thread; 1024*256*4 == B*HW/4
#define TOTAL_PX  4194304.0f  // B*H*W

typedef float v4f __attribute__((ext_vector_type(4)));

// Best-measured configuration (round-1, 186.2 us): two-kernel split,
// NONTEMPORAL loads.
//  - NT loads are required: the harness's 512 MiB poison fills leave LLC full
//    of dirty lines; cache-allocating loads pay eviction write-backs on every
//    miss (+9 us measured, round 4). NT bypasses allocation but still hits
//    LLC-resident input from the previous iteration (~half the 134 MB).
//  - Split beats last-block fusion (round 3, +2.7 us): the 1024 same-line
//    counter atomics serialize at the coherence point on the kernel-end
//    critical path; the tiny finalize kernel reads 32 KB from L2 instead.
__global__ __launch_bounds__(NTHREADS, 4)
void argmax_hist_kernel(const float* __restrict__ masks,
                        unsigned int* __restrict__ partial) {
    const int tid   = threadIdx.x;
    const int b     = blockIdx.x >> 6;          // 64 blocks per batch image
    const int gbase = (blockIdx.x & 63) << 10;  // group offset within image (float4 units)
    const float* bp = masks + (size_t)b * CHW;

    int cnt0 = 0, cnt1 = 0, cnt2 = 0, cnt3 = 0;
    int cnt4 = 0, cnt5 = 0, cnt6 = 0, cnt7 = 0;

    #pragma unroll
    for (int it = 0; it < ITERS; ++it) {
        const v4f* p = (const v4f*)(bp + (size_t)((gbase + it * NTHREADS + tid) << 2));

        // 8 independent 16B nontemporal loads (no-allocate: don't evict the
        // LLC's dirty poison lines; prior-iteration input hits still served)
        v4f v0 = __builtin_nontemporal_load(p + 0 * HWQ);
        v4f v1 = __builtin_nontemporal_load(p + 1 * HWQ);
        v4f v2 = __builtin_nontemporal_load(p + 2 * HWQ);
        v4f v3 = __builtin_nontemporal_load(p + 3 * HWQ);
        v4f v4 = __builtin_nontemporal_load(p + 4 * HWQ);
        v4f v5 = __builtin_nontemporal_load(p + 5 * HWQ);
        v4f v6 = __builtin_nontemporal_load(p + 6 * HWQ);
        v4f v7 = __builtin_nontemporal_load(p + 7 * HWQ);

        float bv0 = v0.x, bv1 = v0.y, bv2 = v0.z, bv3 = v0.w;
        int   bi0 = 0,    bi1 = 0,    bi2 = 0,    bi3 = 0;

        // strict > : first occurrence of max wins (jnp.argmax semantics)
        #define STEP(vv, c)                                                         \
            bi0 = ((vv).x > bv0) ? (c) : bi0;  bv0 = ((vv).x > bv0) ? (vv).x : bv0; \
            bi1 = ((vv).y > bv1) ? (c) : bi1;  bv1 = ((vv).y > bv1) ? (vv).y : bv1; \
            bi2 = ((vv).z > bv2) ? (c) : bi2;  bv2 = ((vv).z > bv2) ? (vv).z : bv2; \
            bi3 = ((vv).w > bv3) ? (c) : bi3;  bv3 = ((vv).w > bv3) ? (vv).w : bv3;
        STEP(v1, 1) STEP(v2, 2) STEP(v3, 3) STEP(v4, 4)
        STEP(v5, 5) STEP(v6, 6) STEP(v7, 7)
        #undef STEP

        // ballot histogram: wave-uniform counts via v_cmp -> s_bcnt1
        #define COUNT(k, acc)                                                        \
            acc += __popcll(__ballot(bi0 == (k))) + __popcll(__ballot(bi1 == (k)))   \
                 + __popcll(__ballot(bi2 == (k))) + __popcll(__ballot(bi3 == (k)));
        COUNT(0, cnt0) COUNT(1, cnt1) COUNT(2, cnt2) COUNT(3, cnt3)
        COUNT(4, cnt4) COUNT(5, cnt5) COUNT(6, cnt6) COUNT(7, cnt7)
        #undef COUNT
    }

    const int lane = tid & 63;
    const int wid  = tid >> 6;
    __shared__ int lds[32];  // [4 waves][8 classes]
    if (lane == 0) {
        lds[wid * 8 + 0] = cnt0;  lds[wid * 8 + 1] = cnt1;
        lds[wid * 8 + 2] = cnt2;  lds[wid * 8 + 3] = cnt3;
        lds[wid * 8 + 4] = cnt4;  lds[wid * 8 + 5] = cnt5;
        lds[wid * 8 + 6] = cnt6;  lds[wid * 8 + 7] = cnt7;
    }
    __syncthreads();
    if (tid < 8) {
        // every block writes all 8 of its slots unconditionally (ws is poisoned)
        unsigned int s = (unsigned int)(lds[tid] + lds[8 + tid] + lds[16 + tid] + lds[24 + tid]);
        partial[blockIdx.x * 8 + tid] = s;
    }
}

// partial: [1024][8] u32 = 8192 u32 = 2048 uint4.  256 threads x 8 uint4 loads,
// all independent -> fully pipelined.  uint4 #m covers classes {0..3} if m even,
// {4..7} if m odd; m = t + 256k keeps parity == parity(t), so each thread's
// 4 accumulators belong to a fixed class group (t&1)*4 + {0..3}.
__global__ __launch_bounds__(256)
void finalize_kernel(const uint4* __restrict__ partial,
                     const float* __restrict__ prev,
                     float* __restrict__ out) {
    __shared__ unsigned int s[256 * 4];
    __shared__ float q[8];
    const int t = threadIdx.x;

    uint4 a = {0u, 0u, 0u, 0u};
    #pragma unroll
    for (int k = 0; k < 8; ++k) {
        uint4 v = partial[t + 256 * k];
        a.x += v.x;  a.y += v.y;  a.z += v.z;  a.w += v.w;
    }
    s[t * 4 + 0] = a.x;  s[t * 4 + 1] = a.y;
    s[t * 4 + 2] = a.z;  s[t * 4 + 3] = a.w;
    __syncthreads();

    if (t < 8) {
        const int grp  = t >> 2;   // parity of contributing threads
        const int comp = t & 3;    // component within uint4
        unsigned int h = 0;
        for (int j = grp; j < 256; j += 2) h += s[j * 4 + comp];
        // exact: h <= 4194304 < 2^24
        float dist = prev[t] * 0.99f + 0.01f * (float)h / TOTAL_PX;
        out[1 + t] = dist;
        float d = (dist - 0.125f) / 0.875f;
        q[t] = d * d;
    }
    __syncthreads();
    if (t == 0) {
        float acc = 0.0f;
        #pragma unroll
        for (int k = 0; k < 8; ++k) acc += q[k];
        out[0] = sqrtf(acc);
    }
}

extern "C" void kernel_launch(void* const* d_in, const int* in_sizes, int n_in,
                              void* d_out, int out_size, void* d_ws, size_t ws_size,
                              hipStream_t stream) {
    const float* masks = (const float*)d_in[0];   // [16,8,512,512] fp32
    const float* prev  = (const float*)d_in[1];   // [8] fp32
    float* out = (float*)d_out;                   // [9]: balance, dist[0..7]
    unsigned int* partial = (unsigned int*)d_ws;  // [1024][8] u32 = 32 KB

    argmax_hist_kernel<<<NBLOCKS, NTHREADS, 0, stream>>>(masks, partial);
    finalize_kernel<<<1, 256, 0, stream>>>((const uint4*)partial, prev, out);
}